// Round 24
// baseline (127.109 us; speedup 1.0000x reference)
//
#include <hip/hip_runtime.h>
#include <hip/hip_bf16.h>

#define HW 262144            // 512*512
#define IW 512
#define TW 64
#define TH 8
#define HLW 66               // TW+2
#define NHALO 660            // 66*10
#define ROWU 40              // ushorts/halo px: 64B data | 4B bscale | pad

typedef __attribute__((ext_vector_type(8))) short short8;
typedef __attribute__((ext_vector_type(4))) float f32x4;
typedef __attribute__((ext_vector_type(4))) unsigned int uint4v;

static __device__ inline unsigned int bpack2(float a, float b) {
  __hip_bfloat16 ha = __float2bfloat16(a);
  __hip_bfloat16 hb = __float2bfloat16(b);
  unsigned short ua = *reinterpret_cast<unsigned short*>(&ha);
  unsigned short ub = *reinterpret_cast<unsigned short*>(&hb);
  return (unsigned int)ua | ((unsigned int)ub << 16);
}

// ---------------- k_gap: GAP of relu(conv1x1(y)), float4 loads --------------
__global__ __launch_bounds__(256) void k_gap(
    const float* __restrict__ y, const float* __restrict__ fuse_w,
    const float* __restrict__ fuse_b, float* __restrict__ partial) {
  __shared__ float fw[80], fb[16];
  __shared__ float red[4][16];
  int tid = threadIdx.x;
  if (tid < 80) fw[tid] = fuse_w[tid];
  if (tid < 16) fb[tid] = fuse_b[tid];
  __syncthreads();

  int b = blockIdx.x >> 7, chunk = blockIdx.x & 127;
  const float* yb = y + (size_t)b * 5 * HW + chunk * 2048;

  float sums[16];
#pragma unroll
  for (int o = 0; o < 16; ++o) sums[o] = 0.f;

#pragma unroll
  for (int i = 0; i < 2048; i += 1024) {
    int p = i + tid * 4;
    f32x4 yv[5];
#pragma unroll
    for (int c = 0; c < 5; ++c)
      yv[c] = *reinterpret_cast<const f32x4*>(&yb[(size_t)c * HW + p]);
#pragma unroll
    for (int o = 0; o < 16; ++o) {
#pragma unroll
      for (int j = 0; j < 4; ++j) {
        float a = fb[o];
#pragma unroll
        for (int c = 0; c < 5; ++c) a = fmaf(fw[o * 5 + c], yv[c][j], a);
        sums[o] += fmaxf(a, 0.f);
      }
    }
  }

  int lane = tid & 63, wv = tid >> 6;
#pragma unroll
  for (int o = 0; o < 16; ++o) {
    float v = sums[o];
    for (int off = 32; off > 0; off >>= 1) v += __shfl_down(v, off);
    if (lane == 0) red[wv][o] = v;
  }
  __syncthreads();
  if (tid < 16)
    partial[blockIdx.x * 16 + tid] =
        red[0][tid] + red[1][tid] + red[2][tid] + red[3][tid];
}

// ---- k_se2: SE MLP -> bd_eff, plus fc_w -> wTab repack (one launch) --------
__global__ __launch_bounds__(256) void k_se2(
    const float* __restrict__ partial, const float* __restrict__ se_w1,
    const float* __restrict__ se_w2, const float* __restrict__ bd_w,
    const float* __restrict__ fc_w, float* __restrict__ bd_eff,
    unsigned short* __restrict__ wTab) {
  int tid = threadIdx.x;
  {
    int b = tid >> 5, sub = tid & 31;
    float g[16];
#pragma unroll
    for (int c = 0; c < 16; ++c) g[c] = 0.f;
#pragma unroll
    for (int k = 0; k < 4; ++k) {
      const float* p = partial + (b * 128 + sub + k * 32) * 16;
#pragma unroll
      for (int c = 0; c < 16; ++c) g[c] += p[c];
    }
#pragma unroll
    for (int c = 0; c < 16; ++c) {
      float v = g[c];
      v += __shfl_xor(v, 1);  v += __shfl_xor(v, 2);
      v += __shfl_xor(v, 4);  v += __shfl_xor(v, 8);
      v += __shfl_xor(v, 16);
      g[c] = v * (1.f / 262144.f);
    }
    if (sub == 0) {
      float h[16];
#pragma unroll
      for (int j = 0; j < 16; ++j) {
        float s = 0.f;
#pragma unroll
        for (int c = 0; c < 16; ++c) s += g[c] * se_w1[j * 16 + c];
        h[j] = fmaxf(s, 0.f);
      }
#pragma unroll
      for (int i = 0; i < 5; ++i) {
        float s = 0.f;
#pragma unroll
        for (int j = 0; j < 16; ++j) s += h[j] * se_w2[i * 16 + j];
        float se = 1.f / (1.f + expf(-s));
        bd_eff[b * 10 + i]     = bd_w[i] * se;
        bd_eff[b * 10 + 5 + i] = bd_w[5 + i] * se;
      }
    }
  }
  for (int i = tid; i < 4608; i += 256) {
    int ci = i & 31, rest = i >> 5;
    int oc = rest & 15, s = rest >> 4;
    float v = fc_w[(oc * 32 + ci) * 9 + s];
    __hip_bfloat16 h = __float2bfloat16(v);
    wTab[i] = *reinterpret_cast<unsigned short*>(&h);
  }
}

// ---- k_main12: r22 kernel + explicit load-phase / pack-phase split ---------
// Staging loads issued upfront into register arrays (8-16 f32x4 in flight
// per thread) before any pack/LDS-write consumes them (G7 idiom).
__global__ __launch_bounds__(256) void k_main12(
    const float* __restrict__ x, const float* __restrict__ y,
    const float* __restrict__ fuse_w, const float* __restrict__ fuse_b,
    const unsigned short* __restrict__ wTab,
    const float* __restrict__ bd_eff, const float* __restrict__ bd_b,
    const float* __restrict__ fc_b,
    const float* __restrict__ fm_w, const float* __restrict__ fm_b,
    const float* __restrict__ cv_w, const float* __restrict__ cv_b,
    float* __restrict__ out) {
  __shared__ unsigned short tile[NHALO * ROWU];   // 52800 B
  __shared__ float s_fw[80], s_fb[16], s_bde[10], s_bdb[2], s_fm[32],
      s_fmb[2], s_cv[16], s_cvb[16], s_fcb[16];

  int tid = threadIdx.x;
  // T1 bijective XCD swizzle: 4096 blocks, 8 XCDs, chunk=512 (one batch/XCD)
  int bid = blockIdx.x;
  int swz = (bid & 7) * 512 + (bid >> 3);
  int bx = swz & 7, by = (swz >> 3) & 63, bsel = swz >> 9;
  int h0 = by * TH;
  int w0 = bx * TW;

  if (tid < 80) s_fw[tid] = fuse_w[tid];
  else if (tid < 96)  s_fb[tid - 80]   = fuse_b[tid - 80];
  else if (tid < 106) s_bde[tid - 96]  = bd_eff[bsel * 10 + tid - 96];
  else if (tid < 108) s_bdb[tid - 106] = bd_b[tid - 106];
  else if (tid < 140) s_fm[tid - 108]  = fm_w[tid - 108];
  else if (tid < 142) s_fmb[tid - 140] = fm_b[tid - 140];
  else if (tid < 158) s_cv[tid - 142]  = cv_w[tid - 142];
  else if (tid < 174) s_cvb[tid - 158] = cv_b[tid - 158];
  else if (tid < 190) s_fcb[tid - 174] = fc_b[tid - 174];

  int lane = tid & 63, wv = tid >> 6;
  int l15 = lane & 15, q = lane >> 4;

  short8 afrag[9];
#pragma unroll
  for (int s = 0; s < 9; ++s)
    afrag[s] = *reinterpret_cast<const short8*>(wTab + (s * 16 + l15) * 32 + q * 8);

  __syncthreads();   // scalar tables ready

  const float* yb = y + (size_t)bsel * 5 * HW;
  const float* xb = x + (size_t)bsel * 16 * HW;

  // ================== staging: LOAD PHASE (all loads issued first) =========
  // x-item 0 (all threads): idx = tid
  f32x4 xva0[4], xvb0[4];
  bool v0;
  {
    int r = tid >> 5, rest = tid & 31, s = rest >> 1, h = rest & 1;
    int gh = h0 - 1 + r;
    v0 = (gh >= 0) & (gh < IW);
    if (v0) {
      const float* xrow =
          xb + (size_t)(8 * h) * HW + (size_t)gh * IW + w0 + s * 4;
#pragma unroll
      for (int cp = 0; cp < 4; ++cp) {
        xva0[cp] = *reinterpret_cast<const f32x4*>(xrow + (size_t)(2 * cp) * HW);
        xvb0[cp] =
            *reinterpret_cast<const f32x4*>(xrow + (size_t)(2 * cp + 1) * HW);
      }
    }
  }
  // x-item 1 (tid>=192): idx = tid + 64
  f32x4 xva1[4], xvb1[4];
  bool v1 = false;
  if (tid >= 192) {
    int idx = tid + 64;
    int r = idx >> 5, rest = idx & 31, s = rest >> 1, h = rest & 1;
    (void)h;
    int gh = h0 - 1 + r;
    v1 = (gh >= 0) & (gh < IW);
    if (v1) {
      const float* xrow =
          xb + (size_t)(8 * (rest & 1)) * HW + (size_t)gh * IW + w0 + s * 4;
#pragma unroll
      for (int cp = 0; cp < 4; ++cp) {
        xva1[cp] = *reinterpret_cast<const f32x4*>(xrow + (size_t)(2 * cp) * HW);
        xvb1[cp] =
            *reinterpret_cast<const f32x4*>(xrow + (size_t)(2 * cp + 1) * HW);
      }
    }
  }
  // fuse item loads (tid<160)
  f32x4 yv[5];
  bool vfu = false;
  if (tid < 160) {
    int r = tid >> 4, s = tid & 15;
    int gh = h0 - 1 + r;
    vfu = (gh >= 0) & (gh < IW);
    if (vfu) {
      const float* yrow = yb + (size_t)gh * IW + w0 + s * 4;
#pragma unroll
      for (int c = 0; c < 5; ++c)
        yv[c] = *reinterpret_cast<const f32x4*>(yrow + (size_t)c * HW);
    }
  }

  // ================== staging: PACK/WRITE PHASE ============================
  // x-item 0
  {
    int r = tid >> 5, rest = tid & 31, s = rest >> 1, h = rest & 1;
    int p0 = r * HLW + 1 + s * 4;
    if (v0) {
      unsigned uu[4][4];
#pragma unroll
      for (int cp = 0; cp < 4; ++cp)
#pragma unroll
        for (int j = 0; j < 4; ++j) uu[j][cp] = bpack2(xva0[cp][j], xvb0[cp][j]);
#pragma unroll
      for (int j = 0; j < 4; ++j)
        reinterpret_cast<uint4v*>(&tile[(p0 + j) * ROWU])[h] =
            uint4v{uu[j][0], uu[j][1], uu[j][2], uu[j][3]};
    } else {
      uint4v z = {0, 0, 0, 0};
#pragma unroll
      for (int j = 0; j < 4; ++j)
        reinterpret_cast<uint4v*>(&tile[(p0 + j) * ROWU])[h] = z;
    }
  }
  // x-item 1
  if (tid >= 192) {
    int idx = tid + 64;
    int r = idx >> 5, rest = idx & 31, s = rest >> 1, h = rest & 1;
    int p0 = r * HLW + 1 + s * 4;
    if (v1) {
      unsigned uu[4][4];
#pragma unroll
      for (int cp = 0; cp < 4; ++cp)
#pragma unroll
        for (int j = 0; j < 4; ++j) uu[j][cp] = bpack2(xva1[cp][j], xvb1[cp][j]);
#pragma unroll
      for (int j = 0; j < 4; ++j)
        reinterpret_cast<uint4v*>(&tile[(p0 + j) * ROWU])[h] =
            uint4v{uu[j][0], uu[j][1], uu[j][2], uu[j][3]};
    } else {
      uint4v z = {0, 0, 0, 0};
#pragma unroll
      for (int j = 0; j < 4; ++j)
        reinterpret_cast<uint4v*>(&tile[(p0 + j) * ROWU])[h] = z;
    }
  }
  // fuse + bscale item
  if (tid < 160) {
    int r = tid >> 4, s = tid & 15;
    int p0 = r * HLW + 1 + s * 4;
    if (vfu) {
      unsigned uu[4][4];
#pragma unroll
      for (int half = 0; half < 2; ++half) {
#pragma unroll
        for (int op = 0; op < 4; ++op) {
          int o = half * 8 + op * 2;
#pragma unroll
          for (int j = 0; j < 4; ++j) {
            float a0 = s_fb[o], a1 = s_fb[o + 1];
#pragma unroll
            for (int c = 0; c < 5; ++c) {
              a0 = fmaf(s_fw[o * 5 + c], yv[c][j], a0);
              a1 = fmaf(s_fw[(o + 1) * 5 + c], yv[c][j], a1);
            }
            uu[j][op] = bpack2(fmaxf(a0, 0.f), fmaxf(a1, 0.f));
          }
        }
#pragma unroll
        for (int j = 0; j < 4; ++j)
          reinterpret_cast<uint4v*>(&tile[(p0 + j) * ROWU])[2 + half] =
              uint4v{uu[j][0], uu[j][1], uu[j][2], uu[j][3]};
      }
#pragma unroll
      for (int j = 0; j < 4; ++j) {
        float bl0 = s_bdb[0], bl1 = s_bdb[1];
#pragma unroll
        for (int c = 0; c < 5; ++c) {
          bl0 = fmaf(s_bde[c], yv[c][j], bl0);
          bl1 = fmaf(s_bde[5 + c], yv[c][j], bl1);
        }
        *reinterpret_cast<float*>(&tile[(p0 + j) * ROWU + 32]) =
            1.f / (1.f + __expf(bl0 - bl1));
      }
    } else {
      uint4v z = {0, 0, 0, 0};
#pragma unroll
      for (int j = 0; j < 4; ++j) {
        uint4v* dst = reinterpret_cast<uint4v*>(&tile[(p0 + j) * ROWU]);
        dst[2] = z; dst[3] = z;
        *reinterpret_cast<float*>(&tile[(p0 + j) * ROWU + 32]) = 0.f;
      }
    }
  } else if (tid < 180) {
    // edge px items: 20 = 10 rows x 2 cols (0 and 65)
    int idx = tid - 160;
    int r = idx >> 1;
    int col = (idx & 1) ? 65 : 0;
    int gh = h0 - 1 + r;
    int p = r * HLW + col;
    int gw = w0 - 1 + col;
    bool valid = (gh >= 0) & (gh < IW) & (gw >= 0) & (gw < IW);
    uint4v* dst = reinterpret_cast<uint4v*>(&tile[p * ROWU]);
    if (valid) {
      int gofs = gh * IW + gw;
      {
        float a0 = xb[gofs],          a1 = xb[HW + gofs];
        float a2 = xb[2 * HW + gofs], a3 = xb[3 * HW + gofs];
        float a4 = xb[4 * HW + gofs], a5 = xb[5 * HW + gofs];
        float a6 = xb[6 * HW + gofs], a7 = xb[7 * HW + gofs];
        dst[0] = uint4v{bpack2(a0, a1), bpack2(a2, a3),
                        bpack2(a4, a5), bpack2(a6, a7)};
      }
      {
        float a0 = xb[8 * HW + gofs],  a1 = xb[9 * HW + gofs];
        float a2 = xb[10 * HW + gofs], a3 = xb[11 * HW + gofs];
        float a4 = xb[12 * HW + gofs], a5 = xb[13 * HW + gofs];
        float a6 = xb[14 * HW + gofs], a7 = xb[15 * HW + gofs];
        dst[1] = uint4v{bpack2(a0, a1), bpack2(a2, a3),
                        bpack2(a4, a5), bpack2(a6, a7)};
      }
      float yvv[5];
#pragma unroll
      for (int c = 0; c < 5; ++c) yvv[c] = yb[c * HW + gofs];
      float fo[8];
#pragma unroll
      for (int o = 0; o < 8; ++o) {
        float a = s_fb[o];
#pragma unroll
        for (int c = 0; c < 5; ++c) a = fmaf(s_fw[o * 5 + c], yvv[c], a);
        fo[o] = fmaxf(a, 0.f);
      }
      dst[2] = uint4v{bpack2(fo[0], fo[1]), bpack2(fo[2], fo[3]),
                      bpack2(fo[4], fo[5]), bpack2(fo[6], fo[7])};
#pragma unroll
      for (int o = 0; o < 8; ++o) {
        float a = s_fb[8 + o];
#pragma unroll
        for (int c = 0; c < 5; ++c) a = fmaf(s_fw[(8 + o) * 5 + c], yvv[c], a);
        fo[o] = fmaxf(a, 0.f);
      }
      dst[3] = uint4v{bpack2(fo[0], fo[1]), bpack2(fo[2], fo[3]),
                      bpack2(fo[4], fo[5]), bpack2(fo[6], fo[7])};
      float bl0 = s_bdb[0], bl1 = s_bdb[1];
#pragma unroll
      for (int c = 0; c < 5; ++c) {
        bl0 = fmaf(s_bde[c], yvv[c], bl0);
        bl1 = fmaf(s_bde[5 + c], yvv[c], bl1);
      }
      *reinterpret_cast<float*>(&tile[p * ROWU + 32]) =
          1.f / (1.f + __expf(bl0 - bl1));
    } else {
      uint4v z = {0, 0, 0, 0};
      dst[0] = z; dst[1] = z; dst[2] = z; dst[3] = z;
      *reinterpret_cast<float*>(&tile[p * ROWU + 32]) = 0.f;
    }
  }
  __syncthreads();

  // ---- compute: 8 groups, tap-major MFMA (8-way ILP) ----
  const char* tb = reinterpret_cast<const char*>(tile);
  unsigned bofs[8];
  f32x4 acc[8];
#pragma unroll
  for (int g = 0; g < 8; ++g) {
    int row = 2 * wv + (g >> 2), c0 = (g & 3) * 16;
    bofs[g] = (unsigned)((row * HLW + c0 + l15) * (ROWU * 2) + q * 16);
    acc[g] = f32x4{0.f, 0.f, 0.f, 0.f};
  }
#pragma unroll
  for (int kh = 0; kh < 3; ++kh) {
#pragma unroll
    for (int kw = 0; kw < 3; ++kw) {
      short8 a = afrag[kh * 3 + kw];
#pragma unroll
      for (int g = 0; g < 8; ++g) {
        short8 bfr = *reinterpret_cast<const short8*>(
            tb + bofs[g] + (kh * HLW + kw) * (ROWU * 2));
        acc[g] = __builtin_amdgcn_mfma_f32_16x16x32_bf16(a, bfr, acc[g], 0, 0, 0);
      }
    }
  }

  float pm0[8], pm1[8];
#pragma unroll
  for (int g = 0; g < 8; ++g) {
    float p0 = 0.f, p1 = 0.f;
#pragma unroll
    for (int j = 0; j < 4; ++j) {
      int oc = q * 4 + j;
      float fv = fmaxf(acc[g][j] + s_fcb[oc], 0.f);
      p0 = fmaf(s_fm[oc], fv, p0);
      p1 = fmaf(s_fm[16 + oc], fv, p1);
    }
    pm0[g] = p0; pm1[g] = p1;
  }
#pragma unroll
  for (int g = 0; g < 8; ++g) pm0[g] += __shfl_xor(pm0[g], 16);
#pragma unroll
  for (int g = 0; g < 8; ++g) pm1[g] += __shfl_xor(pm1[g], 16);
#pragma unroll
  for (int g = 0; g < 8; ++g) pm0[g] += __shfl_xor(pm0[g], 32);
#pragma unroll
  for (int g = 0; g < 8; ++g) pm1[g] += __shfl_xor(pm1[g], 32);

  // sc for all 8 groups (reads bscale from tile BEFORE it is overwritten)
  float scv[8];
#pragma unroll
  for (int g = 0; g < 8; ++g) {
    int row = 2 * wv + (g >> 2), c0 = (g & 3) * 16;
    float mscale =
        1.f / (1.f + __expf((pm0[g] + s_fmb[0]) - (pm1[g] + s_fmb[1])));
    float bsc = *reinterpret_cast<const float*>(
        tb + ((row + 1) * HLW + c0 + l15 + 1) * (ROWU * 2) + 64);
    scv[g] = fminf(fmaxf(mscale + bsc, 0.f), 1.f);
  }

  __syncthreads();   // all waves done reading tile
  float* scbuf = reinterpret_cast<float*>(tile);   // reuse first 2 KB
  if (q == 0) {
#pragma unroll
    for (int g = 0; g < 8; ++g) {
      int row = 2 * wv + (g >> 2), c0 = (g & 3) * 16;
      scbuf[row * 64 + c0 + l15] = scv[g];
    }
  }
  __syncthreads();

  // ---- store phase: 8 f32x4 stores/thread, 1 KiB contiguous per wave-instr -
  float* outb = out + (size_t)bsel * 16 * HW;
#pragma unroll
  for (int it = 0; it < 8; ++it) {
    int t = it * 256 + tid;            // [0, 2048): (oc, px4)
    int oc = t >> 7;                   // 128 f32x4 per oc
    int p4 = t & 127;
    int prow = p4 >> 4, pc = (p4 & 15) * 4;
    f32x4 sv = *reinterpret_cast<const f32x4*>(&scbuf[prow * 64 + pc]);
    float cw = s_cv[oc], cb = s_cvb[oc];
    f32x4 ov = {fmaf(cw, sv[0], cb), fmaf(cw, sv[1], cb),
                fmaf(cw, sv[2], cb), fmaf(cw, sv[3], cb)};
    *reinterpret_cast<f32x4*>(
        &outb[(size_t)oc * HW + (h0 + prow) * IW + w0 + pc]) = ov;
  }
}

extern "C" void kernel_launch(void* const* d_in, const int* in_sizes, int n_in,
                              void* d_out, int out_size, void* d_ws, size_t ws_size,
                              hipStream_t stream) {
  const float* x      = (const float*)d_in[0];
  const float* y      = (const float*)d_in[1];
  const float* fuse_w = (const float*)d_in[2];
  const float* fuse_b = (const float*)d_in[3];
  const float* se_w1  = (const float*)d_in[4];
  const float* se_w2  = (const float*)d_in[5];
  const float* bd_w   = (const float*)d_in[6];
  const float* bd_b   = (const float*)d_in[7];
  const float* fc_w   = (const float*)d_in[8];
  const float* fc_b   = (const float*)d_in[9];
  const float* fm_w   = (const float*)d_in[10];
  const float* fm_b   = (const float*)d_in[11];
  const float* cv_w   = (const float*)d_in[12];
  const float* cv_b   = (const float*)d_in[13];
  float* out = (float*)d_out;

  char* ws = (char*)d_ws;
  float* partial = (float*)ws;                          // 64 KB
  float* bd_eff  = partial + 1024 * 16;                 // 320 B
  unsigned short* wTab = (unsigned short*)(ws + 65856); // 9216 B

  k_gap<<<1024, 256, 0, stream>>>(y, fuse_w, fuse_b, partial);
  k_se2<<<1, 256, 0, stream>>>(partial, se_w1, se_w2, bd_w, fc_w, bd_eff,
                               wTab);
  k_main12<<<4096, 256, 0, stream>>>(
      x, y, fuse_w, fuse_b, wTab, bd_eff, bd_b, fc_b, fm_w, fm_b, cv_w, cv_b,
      out);
}

// Round 25
// 114.656 us; speedup vs baseline: 1.1086x; 1.1086x over previous
//
#include <hip/hip_runtime.h>
#include <hip/hip_bf16.h>

#define HW 262144            // 512*512
#define IW 512
#define TW 64
#define TH 8
#define HLW 66               // TW+2
#define NHALO 660            // 66*10
#define ROWU 40              // ushorts/halo px: 64B data | 4B bscale | pad

typedef __attribute__((ext_vector_type(8))) short short8;
typedef __attribute__((ext_vector_type(4))) float f32x4;
typedef __attribute__((ext_vector_type(4))) unsigned int uint4v;

static __device__ inline unsigned int bpack2(float a, float b) {
  __hip_bfloat16 ha = __float2bfloat16(a);
  __hip_bfloat16 hb = __float2bfloat16(b);
  unsigned short ua = *reinterpret_cast<unsigned short*>(&ha);
  unsigned short ub = *reinterpret_cast<unsigned short*>(&hb);
  return (unsigned int)ua | ((unsigned int)ub << 16);
}

// ---------------- k_gap: GAP of relu(conv1x1(y)), float4 loads --------------
__global__ __launch_bounds__(256) void k_gap(
    const float* __restrict__ y, const float* __restrict__ fuse_w,
    const float* __restrict__ fuse_b, float* __restrict__ partial) {
  __shared__ float fw[80], fb[16];
  __shared__ float red[4][16];
  int tid = threadIdx.x;
  if (tid < 80) fw[tid] = fuse_w[tid];
  if (tid < 16) fb[tid] = fuse_b[tid];
  __syncthreads();

  int b = blockIdx.x >> 7, chunk = blockIdx.x & 127;
  const float* yb = y + (size_t)b * 5 * HW + chunk * 2048;

  float sums[16];
#pragma unroll
  for (int o = 0; o < 16; ++o) sums[o] = 0.f;

#pragma unroll
  for (int i = 0; i < 2048; i += 1024) {
    int p = i + tid * 4;
    f32x4 yv[5];
#pragma unroll
    for (int c = 0; c < 5; ++c)
      yv[c] = *reinterpret_cast<const f32x4*>(&yb[(size_t)c * HW + p]);
#pragma unroll
    for (int o = 0; o < 16; ++o) {
#pragma unroll
      for (int j = 0; j < 4; ++j) {
        float a = fb[o];
#pragma unroll
        for (int c = 0; c < 5; ++c) a = fmaf(fw[o * 5 + c], yv[c][j], a);
        sums[o] += fmaxf(a, 0.f);
      }
    }
  }

  int lane = tid & 63, wv = tid >> 6;
#pragma unroll
  for (int o = 0; o < 16; ++o) {
    float v = sums[o];
    for (int off = 32; off > 0; off >>= 1) v += __shfl_down(v, off);
    if (lane == 0) red[wv][o] = v;
  }
  __syncthreads();
  if (tid < 16)
    partial[blockIdx.x * 16 + tid] =
        red[0][tid] + red[1][tid] + red[2][tid] + red[3][tid];
}

// ---- k_se2: SE MLP -> bd_eff, plus fc_w -> wTab repack (one launch) --------
__global__ __launch_bounds__(256) void k_se2(
    const float* __restrict__ partial, const float* __restrict__ se_w1,
    const float* __restrict__ se_w2, const float* __restrict__ bd_w,
    const float* __restrict__ fc_w, float* __restrict__ bd_eff,
    unsigned short* __restrict__ wTab) {
  int tid = threadIdx.x;
  {
    int b = tid >> 5, sub = tid & 31;
    float g[16];
#pragma unroll
    for (int c = 0; c < 16; ++c) g[c] = 0.f;
#pragma unroll
    for (int k = 0; k < 4; ++k) {
      const float* p = partial + (b * 128 + sub + k * 32) * 16;
#pragma unroll
      for (int c = 0; c < 16; ++c) g[c] += p[c];
    }
#pragma unroll
    for (int c = 0; c < 16; ++c) {
      float v = g[c];
      v += __shfl_xor(v, 1);  v += __shfl_xor(v, 2);
      v += __shfl_xor(v, 4);  v += __shfl_xor(v, 8);
      v += __shfl_xor(v, 16);
      g[c] = v * (1.f / 262144.f);
    }
    if (sub == 0) {
      float h[16];
#pragma unroll
      for (int j = 0; j < 16; ++j) {
        float s = 0.f;
#pragma unroll
        for (int c = 0; c < 16; ++c) s += g[c] * se_w1[j * 16 + c];
        h[j] = fmaxf(s, 0.f);
      }
#pragma unroll
      for (int i = 0; i < 5; ++i) {
        float s = 0.f;
#pragma unroll
        for (int j = 0; j < 16; ++j) s += h[j] * se_w2[i * 16 + j];
        float se = 1.f / (1.f + expf(-s));
        bd_eff[b * 10 + i]     = bd_w[i] * se;
        bd_eff[b * 10 + 5 + i] = bd_w[5 + i] * se;
      }
    }
  }
  for (int i = tid; i < 4608; i += 256) {
    int ci = i & 31, rest = i >> 5;
    int oc = rest & 15, s = rest >> 4;
    float v = fc_w[(oc * 32 + ci) * 9 + s];
    __hip_bfloat16 h = __float2bfloat16(v);
    wTab[i] = *reinterpret_cast<unsigned short*>(&h);
  }
}

// ---- k_main11: best measured conv (r23): balanced staging + edge halves ----
__global__ __launch_bounds__(256) void k_main11(
    const float* __restrict__ x, const float* __restrict__ y,
    const float* __restrict__ fuse_w, const float* __restrict__ fuse_b,
    const unsigned short* __restrict__ wTab,
    const float* __restrict__ bd_eff, const float* __restrict__ bd_b,
    const float* __restrict__ fc_b,
    const float* __restrict__ fm_w, const float* __restrict__ fm_b,
    const float* __restrict__ cv_w, const float* __restrict__ cv_b,
    float* __restrict__ out) {
  __shared__ unsigned short tile[NHALO * ROWU];   // 52800 B
  __shared__ float s_fw[80], s_fb[16], s_bde[10], s_bdb[2], s_fm[32],
      s_fmb[2], s_cv[16], s_cvb[16], s_fcb[16];

  int tid = threadIdx.x;
  // T1 bijective XCD swizzle: 4096 blocks, 8 XCDs, chunk=512 (one batch/XCD)
  int bid = blockIdx.x;
  int swz = (bid & 7) * 512 + (bid >> 3);
  int bx = swz & 7, by = (swz >> 3) & 63, bsel = swz >> 9;
  int h0 = by * TH;
  int w0 = bx * TW;

  if (tid < 80) s_fw[tid] = fuse_w[tid];
  else if (tid < 96)  s_fb[tid - 80]   = fuse_b[tid - 80];
  else if (tid < 106) s_bde[tid - 96]  = bd_eff[bsel * 10 + tid - 96];
  else if (tid < 108) s_bdb[tid - 106] = bd_b[tid - 106];
  else if (tid < 140) s_fm[tid - 108]  = fm_w[tid - 108];
  else if (tid < 142) s_fmb[tid - 140] = fm_b[tid - 140];
  else if (tid < 158) s_cv[tid - 142]  = cv_w[tid - 142];
  else if (tid < 174) s_cvb[tid - 158] = cv_b[tid - 158];
  else if (tid < 190) s_fcb[tid - 174] = fc_b[tid - 174];

  int lane = tid & 63, wv = tid >> 6;
  int l15 = lane & 15, q = lane >> 4;

  short8 afrag[9];
#pragma unroll
  for (int s = 0; s < 9; ++s)
    afrag[s] = *reinterpret_cast<const short8*>(wTab + (s * 16 + l15) * 32 + q * 8);

  __syncthreads();   // scalar tables ready

  const float* yb = y + (size_t)bsel * 5 * HW;
  const float* xb = x + (size_t)bsel * 16 * HW;

  // ---- x-channel items ----
  auto xitem = [&](int idx) {
    int r = idx >> 5;                 // 0..9
    int rest = idx & 31;
    int s = rest >> 1;                // 0..15 (4-px segment)
    int h = rest & 1;                 // channel half
    int gh = h0 - 1 + r;
    int p0 = r * HLW + 1 + s * 4;
    if (gh >= 0 && gh < IW) {
      const float* xrow = xb + (size_t)(8 * h) * HW + (size_t)gh * IW + w0 + s * 4;
      unsigned uu[4][4];
#pragma unroll
      for (int cp = 0; cp < 4; ++cp) {
        f32x4 va = *reinterpret_cast<const f32x4*>(xrow + (size_t)(2 * cp) * HW);
        f32x4 vb =
            *reinterpret_cast<const f32x4*>(xrow + (size_t)(2 * cp + 1) * HW);
#pragma unroll
        for (int j = 0; j < 4; ++j) uu[j][cp] = bpack2(va[j], vb[j]);
      }
#pragma unroll
      for (int j = 0; j < 4; ++j)
        reinterpret_cast<uint4v*>(&tile[(p0 + j) * ROWU])[h] =
            uint4v{uu[j][0], uu[j][1], uu[j][2], uu[j][3]};
    } else {
      uint4v z = {0, 0, 0, 0};
#pragma unroll
      for (int j = 0; j < 4; ++j)
        reinterpret_cast<uint4v*>(&tile[(p0 + j) * ROWU])[h] = z;
    }
  };

  xitem(tid);
  if (tid >= 192) xitem(tid + 64);

  if (tid < 160) {
    // ---- fuse + bscale items ----
    int r = tid >> 4, s = tid & 15;
    int gh = h0 - 1 + r;
    int p0 = r * HLW + 1 + s * 4;
    if (gh >= 0 && gh < IW) {
      const float* yrow = yb + (size_t)gh * IW + w0 + s * 4;
      f32x4 yv[5];
#pragma unroll
      for (int c = 0; c < 5; ++c)
        yv[c] = *reinterpret_cast<const f32x4*>(yrow + (size_t)c * HW);
      unsigned uu[4][4];
#pragma unroll
      for (int half = 0; half < 2; ++half) {
#pragma unroll
        for (int op = 0; op < 4; ++op) {
          int o = half * 8 + op * 2;
#pragma unroll
          for (int j = 0; j < 4; ++j) {
            float a0 = s_fb[o], a1 = s_fb[o + 1];
#pragma unroll
            for (int c = 0; c < 5; ++c) {
              a0 = fmaf(s_fw[o * 5 + c], yv[c][j], a0);
              a1 = fmaf(s_fw[(o + 1) * 5 + c], yv[c][j], a1);
            }
            uu[j][op] = bpack2(fmaxf(a0, 0.f), fmaxf(a1, 0.f));
          }
        }
#pragma unroll
        for (int j = 0; j < 4; ++j)
          reinterpret_cast<uint4v*>(&tile[(p0 + j) * ROWU])[2 + half] =
              uint4v{uu[j][0], uu[j][1], uu[j][2], uu[j][3]};
      }
#pragma unroll
      for (int j = 0; j < 4; ++j) {
        float bl0 = s_bdb[0], bl1 = s_bdb[1];
#pragma unroll
        for (int c = 0; c < 5; ++c) {
          bl0 = fmaf(s_bde[c], yv[c][j], bl0);
          bl1 = fmaf(s_bde[5 + c], yv[c][j], bl1);
        }
        *reinterpret_cast<float*>(&tile[(p0 + j) * ROWU + 32]) =
            1.f / (1.f + __expf(bl0 - bl1));
      }
    } else {
      uint4v z = {0, 0, 0, 0};
#pragma unroll
      for (int j = 0; j < 4; ++j) {
        uint4v* dst = reinterpret_cast<uint4v*>(&tile[(p0 + j) * ROWU]);
        dst[2] = z; dst[3] = z;
        *reinterpret_cast<float*>(&tile[(p0 + j) * ROWU + 32]) = 0.f;
      }
    }
  } else if (tid >= 180 && tid < 220) {
    // ---- edge half-items: 40 = 20 edge px x {x-half, fuse-half} ----
    int idx = tid - 180;
    int e = idx >> 1;                 // edge px 0..19
    int part = idx & 1;               // 0 = x channels, 1 = fuse+bscale
    int r = e >> 1;
    int col = (e & 1) ? 65 : 0;
    int gh = h0 - 1 + r;
    int p = r * HLW + col;
    int gw = w0 - 1 + col;
    bool valid = (gh >= 0) & (gh < IW) & (gw >= 0) & (gw < IW);
    uint4v* dst = reinterpret_cast<uint4v*>(&tile[p * ROWU]);
    if (part == 0) {
      if (valid) {
        int gofs = gh * IW + gw;
        {
          float a0 = xb[gofs],          a1 = xb[HW + gofs];
          float a2 = xb[2 * HW + gofs], a3 = xb[3 * HW + gofs];
          float a4 = xb[4 * HW + gofs], a5 = xb[5 * HW + gofs];
          float a6 = xb[6 * HW + gofs], a7 = xb[7 * HW + gofs];
          dst[0] = uint4v{bpack2(a0, a1), bpack2(a2, a3),
                          bpack2(a4, a5), bpack2(a6, a7)};
        }
        {
          float a0 = xb[8 * HW + gofs],  a1 = xb[9 * HW + gofs];
          float a2 = xb[10 * HW + gofs], a3 = xb[11 * HW + gofs];
          float a4 = xb[12 * HW + gofs], a5 = xb[13 * HW + gofs];
          float a6 = xb[14 * HW + gofs], a7 = xb[15 * HW + gofs];
          dst[1] = uint4v{bpack2(a0, a1), bpack2(a2, a3),
                          bpack2(a4, a5), bpack2(a6, a7)};
        }
      } else {
        uint4v z = {0, 0, 0, 0};
        dst[0] = z; dst[1] = z;
      }
    } else {
      if (valid) {
        int gofs = gh * IW + gw;
        float yv[5];
#pragma unroll
        for (int c = 0; c < 5; ++c) yv[c] = yb[c * HW + gofs];
        float fo[8];
#pragma unroll
        for (int o = 0; o < 8; ++o) {
          float a = s_fb[o];
#pragma unroll
          for (int c = 0; c < 5; ++c) a = fmaf(s_fw[o * 5 + c], yv[c], a);
          fo[o] = fmaxf(a, 0.f);
        }
        dst[2] = uint4v{bpack2(fo[0], fo[1]), bpack2(fo[2], fo[3]),
                        bpack2(fo[4], fo[5]), bpack2(fo[6], fo[7])};
#pragma unroll
        for (int o = 0; o < 8; ++o) {
          float a = s_fb[8 + o];
#pragma unroll
          for (int c = 0; c < 5; ++c) a = fmaf(s_fw[(8 + o) * 5 + c], yv[c], a);
          fo[o] = fmaxf(a, 0.f);
        }
        dst[3] = uint4v{bpack2(fo[0], fo[1]), bpack2(fo[2], fo[3]),
                        bpack2(fo[4], fo[5]), bpack2(fo[6], fo[7])};
        float bl0 = s_bdb[0], bl1 = s_bdb[1];
#pragma unroll
        for (int c = 0; c < 5; ++c) {
          bl0 = fmaf(s_bde[c], yv[c], bl0);
          bl1 = fmaf(s_bde[5 + c], yv[c], bl1);
        }
        *reinterpret_cast<float*>(&tile[p * ROWU + 32]) =
            1.f / (1.f + __expf(bl0 - bl1));
      } else {
        uint4v z = {0, 0, 0, 0};
        dst[2] = z; dst[3] = z;
        *reinterpret_cast<float*>(&tile[p * ROWU + 32]) = 0.f;
      }
    }
  }
  __syncthreads();

  // ---- compute: 8 groups, tap-major MFMA (8-way ILP) ----
  const char* tb = reinterpret_cast<const char*>(tile);
  unsigned bofs[8];
  f32x4 acc[8];
#pragma unroll
  for (int g = 0; g < 8; ++g) {
    int row = 2 * wv + (g >> 2), c0 = (g & 3) * 16;
    bofs[g] = (unsigned)((row * HLW + c0 + l15) * (ROWU * 2) + q * 16);
    acc[g] = f32x4{0.f, 0.f, 0.f, 0.f};
  }
#pragma unroll
  for (int kh = 0; kh < 3; ++kh) {
#pragma unroll
    for (int kw = 0; kw < 3; ++kw) {
      short8 a = afrag[kh * 3 + kw];
#pragma unroll
      for (int g = 0; g < 8; ++g) {
        short8 bfr = *reinterpret_cast<const short8*>(
            tb + bofs[g] + (kh * HLW + kw) * (ROWU * 2));
        acc[g] = __builtin_amdgcn_mfma_f32_16x16x32_bf16(a, bfr, acc[g], 0, 0, 0);
      }
    }
  }

  float pm0[8], pm1[8];
#pragma unroll
  for (int g = 0; g < 8; ++g) {
    float p0 = 0.f, p1 = 0.f;
#pragma unroll
    for (int j = 0; j < 4; ++j) {
      int oc = q * 4 + j;
      float fv = fmaxf(acc[g][j] + s_fcb[oc], 0.f);
      p0 = fmaf(s_fm[oc], fv, p0);
      p1 = fmaf(s_fm[16 + oc], fv, p1);
    }
    pm0[g] = p0; pm1[g] = p1;
  }
#pragma unroll
  for (int g = 0; g < 8; ++g) pm0[g] += __shfl_xor(pm0[g], 16);
#pragma unroll
  for (int g = 0; g < 8; ++g) pm1[g] += __shfl_xor(pm1[g], 16);
#pragma unroll
  for (int g = 0; g < 8; ++g) pm0[g] += __shfl_xor(pm0[g], 32);
#pragma unroll
  for (int g = 0; g < 8; ++g) pm1[g] += __shfl_xor(pm1[g], 32);

  // sc for all 8 groups (reads bscale from tile BEFORE it is overwritten)
  float scv[8];
#pragma unroll
  for (int g = 0; g < 8; ++g) {
    int row = 2 * wv + (g >> 2), c0 = (g & 3) * 16;
    float mscale =
        1.f / (1.f + __expf((pm0[g] + s_fmb[0]) - (pm1[g] + s_fmb[1])));
    float bsc = *reinterpret_cast<const float*>(
        tb + ((row + 1) * HLW + c0 + l15 + 1) * (ROWU * 2) + 64);
    scv[g] = fminf(fmaxf(mscale + bsc, 0.f), 1.f);
  }

  __syncthreads();   // all waves done reading tile
  float* scbuf = reinterpret_cast<float*>(tile);   // reuse first 2 KB
  if (q == 0) {
#pragma unroll
    for (int g = 0; g < 8; ++g) {
      int row = 2 * wv + (g >> 2), c0 = (g & 3) * 16;
      scbuf[row * 64 + c0 + l15] = scv[g];
    }
  }
  __syncthreads();

  // ---- store phase: 8 f32x4 stores/thread, 1 KiB contiguous per wave-instr -
  float* outb = out + (size_t)bsel * 16 * HW;
#pragma unroll
  for (int it = 0; it < 8; ++it) {
    int t = it * 256 + tid;            // [0, 2048): (oc, px4)
    int oc = t >> 7;                   // 128 f32x4 per oc
    int p4 = t & 127;
    int prow = p4 >> 4, pc = (p4 & 15) * 4;
    f32x4 sv = *reinterpret_cast<const f32x4*>(&scbuf[prow * 64 + pc]);
    float cw = s_cv[oc], cb = s_cvb[oc];
    f32x4 ov = {fmaf(cw, sv[0], cb), fmaf(cw, sv[1], cb),
                fmaf(cw, sv[2], cb), fmaf(cw, sv[3], cb)};
    *reinterpret_cast<f32x4*>(
        &outb[(size_t)oc * HW + (h0 + prow) * IW + w0 + pc]) = ov;
  }
}

extern "C" void kernel_launch(void* const* d_in, const int* in_sizes, int n_in,
                              void* d_out, int out_size, void* d_ws, size_t ws_size,
                              hipStream_t stream) {
  const float* x      = (const float*)d_in[0];
  const float* y      = (const float*)d_in[1];
  const float* fuse_w = (const float*)d_in[2];
  const float* fuse_b = (const float*)d_in[3];
  const float* se_w1  = (const float*)d_in[4];
  const float* se_w2  = (const float*)d_in[5];
  const float* bd_w   = (const float*)d_in[6];
  const float* bd_b   = (const float*)d_in[7];
  const float* fc_w   = (const float*)d_in[8];
  const float* fc_b   = (const float*)d_in[9];
  const float* fm_w   = (const float*)d_in[10];
  const float* fm_b   = (const float*)d_in[11];
  const float* cv_w   = (const float*)d_in[12];
  const float* cv_b   = (const float*)d_in[13];
  float* out = (float*)d_out;

  char* ws = (char*)d_ws;
  float* partial = (float*)ws;                          // 64 KB
  float* bd_eff  = partial + 1024 * 16;                 // 320 B
  unsigned short* wTab = (unsigned short*)(ws + 65856); // 9216 B

  k_gap<<<1024, 256, 0, stream>>>(y, fuse_w, fuse_b, partial);
  k_se2<<<1, 256, 0, stream>>>(partial, se_w1, se_w2, bd_w, fc_w, bd_eff,
                               wTab);
  k_main11<<<4096, 256, 0, stream>>>(
      x, y, fuse_w, fuse_b, wTab, bd_eff, bd_b, fc_b, fm_w, fm_b, cv_w, cv_b,
      out);
}